// Round 1
// baseline (225.675 us; speedup 1.0000x reference)
//
#include <hip/hip_runtime.h>
#include <math.h>

#define BB 32
#define SS 4096
#define HH 512
#define CHUNKS 32
#define ROWS_PER_CHUNK (SS / CHUNKS)  // 128

// ws layout (float offsets):
//  targets  [2][B][H]          @ 0        (32768)
//  scores   [2][B][S]          @ 32768    (262144)
//  pml      [2][B][CHUNKS][2]  @ 294912   (4096)
//  pacc     [2][B][CHUNKS][H]  @ 299008   (1048576)
//  weighted [2][B][H]          @ 1347584  (32768)
// total 1380352 floats = 5.27 MB
#define WS_TARGETS 0
#define WS_SCORES 32768
#define WS_PML 294912
#define WS_PACC 299008
#define WS_WEIGHTED 1347584

// ---------------------------------------------------------------- K1: targets
__global__ __launch_bounds__(256) void k_target(
    const float* __restrict__ tree_in, const float* __restrict__ text_in,
    const float* __restrict__ W_in, float* __restrict__ ws)
{
    const int b = blockIdx.x;
    const int br = blockIdx.y;
    const float* inp = (br == 0 ? tree_in : text_in) + b * HH;

    __shared__ float sin_[HH];
    for (int i = threadIdx.x; i < HH; i += 256) sin_[i] = inp[i];
    __syncthreads();

    const int h0 = threadIdx.x, h1 = threadIdx.x + 256;
    float acc0 = 0.f, acc1 = 0.f;
    for (int k = 0; k < HH; ++k) {
        const float x = sin_[k];
        acc0 += x * W_in[k * HH + h0];
        acc1 += x * W_in[k * HH + h1];
    }
    float* tgt = ws + WS_TARGETS + (size_t)(br * BB + b) * HH;
    tgt[h0] = acc0;
    tgt[h1] = acc1;
}

// ------------------------------------------------- K2: flash pass over context
__global__ __launch_bounds__(256) void k_flash(
    const float* __restrict__ tree_ctx, const float* __restrict__ text_ctx,
    const float* __restrict__ tree_mask, const float* __restrict__ text_mask,
    float* __restrict__ ws)
{
    const int chunk = blockIdx.x;
    const int b = blockIdx.y;
    const int br = blockIdx.z;

    const float* ctx = (br == 0 ? tree_ctx : text_ctx) + (size_t)b * SS * HH;
    const float* mask = (br == 0 ? tree_mask : text_mask) + (size_t)b * SS;
    const float* tgt = ws + WS_TARGETS + (size_t)(br * BB + b) * HH;
    float* scores = ws + WS_SCORES + (size_t)(br * BB + b) * SS;

    const int wave = threadIdx.x >> 6;
    const int lane = threadIdx.x & 63;

    const float4* tgt4 = (const float4*)tgt;
    const float4 t0 = tgt4[lane];
    const float4 t1 = tgt4[lane + 64];

    float m = -INFINITY, l = 0.f;
    float4 a0 = make_float4(0.f, 0.f, 0.f, 0.f);
    float4 a1 = make_float4(0.f, 0.f, 0.f, 0.f);

    const int s_base = chunk * ROWS_PER_CHUNK;
    for (int i = wave; i < ROWS_PER_CHUNK; i += 4) {
        const int s = s_base + i;
        const float4* row = (const float4*)(ctx + (size_t)s * HH);
        const float4 c0 = row[lane];
        const float4 c1 = row[lane + 64];

        float d = c0.x * t0.x + c0.y * t0.y + c0.z * t0.z + c0.w * t0.w
                + c1.x * t1.x + c1.y * t1.y + c1.z * t1.z + c1.w * t1.w;
        #pragma unroll
        for (int off = 32; off >= 1; off >>= 1) d += __shfl_xor(d, off);

        const float sc = d * mask[s];
        if (lane == 0) scores[s] = sc;

        const float mnew = fmaxf(m, sc);
        const float scale = __expf(m - mnew);   // m==-inf -> 0
        const float p = __expf(sc - mnew);
        l = l * scale + p;
        a0.x = a0.x * scale + p * c0.x;
        a0.y = a0.y * scale + p * c0.y;
        a0.z = a0.z * scale + p * c0.z;
        a0.w = a0.w * scale + p * c0.w;
        a1.x = a1.x * scale + p * c1.x;
        a1.y = a1.y * scale + p * c1.y;
        a1.z = a1.z * scale + p * c1.z;
        a1.w = a1.w * scale + p * c1.w;
        m = mnew;
    }

    // block combine (4 wave-partials -> 1 block-partial)
    __shared__ float lm[4], ll[4];
    __shared__ float lacc[4][HH];   // 8 KB
    if (lane == 0) { lm[wave] = m; ll[wave] = l; }
    ((float4*)lacc[wave])[lane] = a0;
    ((float4*)lacc[wave])[lane + 64] = a1;
    __syncthreads();

    const float M = fmaxf(fmaxf(lm[0], lm[1]), fmaxf(lm[2], lm[3]));
    const float e0 = __expf(lm[0] - M);
    const float e1 = __expf(lm[1] - M);
    const float e2 = __expf(lm[2] - M);
    const float e3 = __expf(lm[3] - M);

    float* pml = ws + WS_PML + (size_t)((br * BB + b) * CHUNKS + chunk) * 2;
    float* pacc = ws + WS_PACC + (size_t)((br * BB + b) * CHUNKS + chunk) * HH;
    for (int h = threadIdx.x; h < HH; h += 256)
        pacc[h] = lacc[0][h] * e0 + lacc[1][h] * e1 + lacc[2][h] * e2 + lacc[3][h] * e3;
    if (threadIdx.x == 0) {
        pml[0] = M;
        pml[1] = ll[0] * e0 + ll[1] * e1 + ll[2] * e2 + ll[3] * e3;
    }
}

// -------------------------------- K3: merge partials -> weighted, att outputs
__global__ __launch_bounds__(256) void k_combine(
    const float* __restrict__ ws_ro, float* __restrict__ ws, float* __restrict__ out)
{
    const int b = blockIdx.x;
    const int br = blockIdx.y;

    const float* pml = ws_ro + WS_PML + (size_t)(br * BB + b) * CHUNKS * 2;
    const float* pacc = ws_ro + WS_PACC + (size_t)(br * BB + b) * CHUNKS * HH;

    __shared__ float esc[CHUNKS];
    float M = -INFINITY;
    for (int c = 0; c < CHUNKS; ++c) M = fmaxf(M, pml[2 * c]);
    float L = 0.f;
    for (int c = 0; c < CHUNKS; ++c) L += pml[2 * c + 1] * __expf(pml[2 * c] - M);
    const float invL = 1.f / L;
    for (int c = threadIdx.x; c < CHUNKS; c += 256) esc[c] = __expf(pml[2 * c] - M);
    __syncthreads();

    float* wt = ws + WS_WEIGHTED + (size_t)(br * BB + b) * HH;
    for (int h = threadIdx.x; h < HH; h += 256) {
        float acc = 0.f;
        for (int c = 0; c < CHUNKS; ++c) acc += pacc[(size_t)c * HH + h] * esc[c];
        wt[h] = acc * invL;
    }

    const float* scores = ws_ro + WS_SCORES + (size_t)(br * BB + b) * SS;
    float* att = out + BB * HH + (size_t)(br * BB + b) * SS;
    for (int s = threadIdx.x; s < SS; s += 256)
        att[s] = __expf(scores[s] - M) * invL;
}

// --------------------------------------- K4: combined = tanh(concat @ W_out)
__global__ __launch_bounds__(256) void k_final(
    const float* __restrict__ tree_in, const float* __restrict__ text_in,
    const float* __restrict__ W_out, const float* __restrict__ ws,
    float* __restrict__ out)
{
    const int hb = blockIdx.x;   // 0..1
    const int b = blockIdx.y;

    __shared__ float comb[4 * HH];  // 8 KB
    const float* tw = ws + WS_WEIGHTED + (size_t)(0 * BB + b) * HH;
    const float* xw = ws + WS_WEIGHTED + (size_t)(1 * BB + b) * HH;
    for (int i = threadIdx.x; i < HH; i += 256) {
        comb[i] = tw[i];
        comb[HH + i] = tree_in[b * HH + i];
        comb[2 * HH + i] = xw[i];
        comb[3 * HH + i] = text_in[b * HH + i];
    }
    __syncthreads();

    const int h = hb * 256 + threadIdx.x;
    float acc = 0.f;
    for (int k = 0; k < 4 * HH; ++k)
        acc += comb[k] * W_out[(size_t)k * HH + h];
    out[b * HH + h] = tanhf(acc);
}

// ---------------------------------------------------------------------- launch
extern "C" void kernel_launch(void* const* d_in, const int* in_sizes, int n_in,
                              void* d_out, int out_size, void* d_ws, size_t ws_size,
                              hipStream_t stream)
{
    const float* tree_inputs  = (const float*)d_in[0];
    const float* tree_context = (const float*)d_in[1];
    const float* text_inputs  = (const float*)d_in[2];
    const float* text_context = (const float*)d_in[3];
    const float* tree_mask    = (const float*)d_in[4];
    const float* text_mask    = (const float*)d_in[5];
    const float* W_in         = (const float*)d_in[6];
    const float* W_out        = (const float*)d_in[7];
    float* out = (float*)d_out;
    float* ws = (float*)d_ws;

    k_target<<<dim3(BB, 2), 256, 0, stream>>>(tree_inputs, text_inputs, W_in, ws);
    k_flash<<<dim3(CHUNKS, BB, 2), 256, 0, stream>>>(tree_context, text_context,
                                                     tree_mask, text_mask, ws);
    k_combine<<<dim3(BB, 2), 256, 0, stream>>>(ws, ws, out);
    k_final<<<dim3(2, BB), 256, 0, stream>>>(tree_inputs, text_inputs, W_out, ws, out);
}